// Round 2
// baseline (137.233 us; speedup 1.0000x reference)
//
#include <hip/hip_runtime.h>
#include <math.h>

typedef float  f32x4  __attribute__((ext_vector_type(4)));
typedef int    int4v  __attribute__((ext_vector_type(4)));
typedef int    int8v  __attribute__((ext_vector_type(8)));

constexpr float MARGIN    = 0.1f;
constexpr float SCALE_POS = 2.0f;
constexpr float SCALE_NEG = 50.0f;
constexpr float THRESH    = 0.5f;
constexpr float ONE_EPS   = 1.0f - 1e-5f;
constexpr float LOG2E     = 1.4426950408889634f;
constexpr float BC        = -(SCALE_NEG * THRESH * LOG2E);   // -36.0674
// elements with a*v + BC < -30 contribute < 2^-30 ~ 9e-10 each to neg_sum;
// total skipped mass <= 8192*9e-10/50 ~ 1.6e-7 on the loss (threshold 2e-2).
constexpr float VCUT_COEF = (36.0674f - 30.0f) / (SCALE_NEG * LOG2E);  // ~0.08412 (in S units)

constexpr int D      = 192;   // feature dim
constexpr int KP     = 256;   // K padded to 2x128 for mfma_scale 16x16x128
constexpr int RT     = 4;     // row-tiles (16 rows) per wave
constexpr int RPW    = 64;    // rows per wave
constexpr int RPB    = 256;   // rows per block (4 waves)
constexpr int CSPLIT = 16;    // column splits for pass2 (512 WGs)

// symmetric pass1 tiling: 32 blocks of 256 rows/cols; upper triangle only
constexpr int NSLOT  = 32;                      // 256-col partial slots
constexpr int CBLK   = 256;                     // col-block width in pass1
constexpr int NTILES = CBLK / 16;               // 16 col-tiles per block
constexpr int NPAIR  = (NSLOT * (NSLOT - 1)) / 2;  // 496 off-diagonal pairs

// fp8 packed fragment layout (K=256 = 2 frags of 128):
// pk8[tile*4096 + g*2048 + (q*16 + c)*32 + o] = fp8(f[row=tile*16+c][k=g*128+q*32+o])
// (k >= 192 zero-padded). One wave frag load = contiguous 2KB.
constexpr int TILE_B8 = 4096;   // bytes per 16-row tile
constexpr int SCALE1  = 0x7f7f7f7f;  // e8m0 = 127 -> 2^0 = 1.0 for every block

__device__ inline float fast_exp2(float x) {
#if __has_builtin(__builtin_amdgcn_exp2f)
  return __builtin_amdgcn_exp2f(x);
#else
  return exp2f(x);
#endif
}

// pin a fragment in registers (prevent re-materialization of the global load
// inside the K-loop -- R6 showed the compiler reloads A per tile otherwise)
__device__ inline void pin_frag8(int8v& v) {
  asm volatile("" : "+v"(v));
}

// ---------------- prep: fp32->fp8 pack (blocks 0..63) + buckets (block 64) ----------------
__global__ __launch_bounds__(1024) void k_prep(
    const float* __restrict__ f, unsigned char* __restrict__ pk8, int nrows,
    const int* __restrict__ labs, int* __restrict__ hist_g, int* __restrict__ offs_g,
    int* __restrict__ bucket, float* __restrict__ accum, int n)
{
  if (blockIdx.x < 64) {
    // ---- pack: tid = r*8 + j; j indexes a 32-wide K chunk (g=j>>2, q=j&3); j>=6 -> zeros
    int gid = blockIdx.x * 1024 + threadIdx.x;
    int r = gid >> 3, j = gid & 7;
    if (r >= nrows) return;
    float x[32];
    if (j < 6) {
      const float* src = f + (size_t)r * D + j * 32;
#pragma unroll
      for (int i = 0; i < 8; ++i) {
        float4 v = *(const float4*)(src + i * 4);
        x[i * 4 + 0] = v.x; x[i * 4 + 1] = v.y; x[i * 4 + 2] = v.z; x[i * 4 + 3] = v.w;
      }
    } else {
#pragma unroll
      for (int i = 0; i < 32; ++i) x[i] = 0.f;
    }
    union { int s[8]; int8v v; } u;
#pragma unroll
    for (int i = 0; i < 8; ++i) {
      int p = __builtin_amdgcn_cvt_pk_fp8_f32(x[i * 4 + 0], x[i * 4 + 1], 0, false);
      p     = __builtin_amdgcn_cvt_pk_fp8_f32(x[i * 4 + 2], x[i * 4 + 3], p, true);
      u.s[i] = p;
    }
    int tile = r >> 4, c = r & 15, g = j >> 2, qq = j & 3;
    *(int8v*)(pk8 + (size_t)tile * TILE_B8 + g * 2048 + (qq * 16 + c) * 32) = u.v;
    return;
  }

  // ---- buckets: hist + scan + scatter + accum zero (single block)
  __shared__ int histL[4096];
  __shared__ int offsL[4096];
  __shared__ int scanb[1024];
  const int t = threadIdx.x;

  if (t < 3) accum[t] = 0.f;     // [0]=loss sum, [1]=no-neg count, [2]=ticket
  for (int i = t; i < 4096; i += 1024) histL[i] = 0;
  __syncthreads();
  for (int i = t; i < n; i += 1024) atomicAdd(&histL[labs[i]], 1);
  __syncthreads();
  int base = t * 4;
  int v[4]; int ls = 0;
  for (int k = 0; k < 4; ++k) { v[k] = ls; ls += histL[base + k]; }
  scanb[t] = ls;
  __syncthreads();
  for (int o = 1; o < 1024; o <<= 1) {
    int x = (t >= o) ? scanb[t - o] : 0;
    __syncthreads();
    scanb[t] += x;
    __syncthreads();
  }
  int ebase = scanb[t] - ls;
  for (int k = 0; k < 4; ++k) {
    offsL[base + k] = ebase + v[k];
    offs_g[base + k] = ebase + v[k];
    hist_g[base + k] = histL[base + k];
  }
  __syncthreads();
  for (int i = t; i < 4096; i += 1024) histL[i] = 0;
  __syncthreads();
  for (int i = t; i < n; i += 1024) {
    int lab = labs[i];
    int p = atomicAdd(&histL[lab], 1);
    bucket[offsL[lab] + p] = i;
  }
}

// ---------------- pass 1 (SYMMETRIC): sumsq + max over negatives ----------------
// Upper-triangle 256x256 block pairs (i<=j). Off-diagonal WGs emit BOTH the
// row-side partials (slot j, rows of block i) and, via sim(r,c)=sim(c,r), the
// col-side partials (slot i, rows of block j). Every (slot,row) pair has
// exactly one writer -> no atomics. Diagonals (i==j) emit row-side only.
__global__ __launch_bounds__(256, 2) void k_pass1(
    const unsigned char* __restrict__ pk8, const int* __restrict__ labs,
    float* __restrict__ sumsqP, float* __restrict__ maxnegP, int N)
{
  __shared__ int   ldsLab[CBLK];
  __shared__ float colS[4][CBLK];
  __shared__ float colM[4][CBLK];

  const int tid  = threadIdx.x;
  const int lane = tid & 63;
  const int w    = tid >> 6;
  const int q    = lane >> 4;
  const int c    = lane & 15;

  // pair decode: bids [0,NPAIR) = off-diagonal (i<j); [NPAIR, NPAIR+32) = diagonal
  // (diagonals last: they are lighter, good tail for the 528-WG grid @ 2/CU)
  int i, j;
  if ((int)blockIdx.x < NPAIR) {
    int t = blockIdx.x; i = 0;
    while (t >= NSLOT - 1 - i) { t -= NSLOT - 1 - i; ++i; }
    j = i + 1 + t;
  } else {
    i = j = blockIdx.x - NPAIR;
  }
  const bool offd = (i != j);
  const int rowbase = i * CBLK + w * RPW;
  const int ctile0  = j * NTILES;

  ldsLab[tid] = labs[(j * CBLK + tid) >> 1];

  // A fragments: load once, pin resident (RT x 2 x 8 VGPR = 64)
  int8v afr[RT][2];
#pragma unroll
  for (int rt = 0; rt < RT; ++rt)
#pragma unroll
    for (int g = 0; g < 2; ++g) {
      afr[rt][g] = *(const int8v*)(pk8 + (size_t)((rowbase >> 4) + rt) * TILE_B8 + g * 2048 + lane * 32);
      pin_frag8(afr[rt][g]);
    }

  int labrow[RT][4];
#pragma unroll
  for (int rt = 0; rt < RT; ++rt)
#pragma unroll
    for (int rr = 0; rr < 4; ++rr)
      labrow[rt][rr] = labs[(rowbase + rt * 16 + q * 4 + rr) >> 1];

  float ssq[RT][4], mxn[RT][4];
#pragma unroll
  for (int rt = 0; rt < RT; ++rt)
#pragma unroll
    for (int rr = 0; rr < 4; ++rr) { ssq[rt][rr] = 0.f; mxn[rt][rr] = -INFINITY; }

  __syncthreads();   // ldsLab ready

  auto loadB = [&](int tile, int8v (&bf)[2]) {
    const unsigned char* bp = pk8 + (size_t)(ctile0 + tile) * TILE_B8 + lane * 32;
#pragma unroll
    for (int g = 0; g < 2; ++g) bf[g] = *(const int8v*)(bp + g * 2048);
  };
  auto compute = [&](const int8v (&bf)[2], int t) {
    const int labcol = ldsLab[t * 16 + c];
    f32x4 acc[RT];
#pragma unroll
    for (int rt = 0; rt < RT; ++rt) acc[rt] = 0.f;
#pragma unroll
    for (int g = 0; g < 2; ++g)
#pragma unroll
      for (int rt = 0; rt < RT; ++rt)
        acc[rt] = __builtin_amdgcn_mfma_scale_f32_16x16x128_f8f6f4(
            afr[rt][g], bf[g], acc[rt], 0, 0, 0, SCALE1, 0, SCALE1);
    float csA = 0.f, cmA = -INFINITY;
#pragma unroll
    for (int rt = 0; rt < RT; ++rt)
#pragma unroll
      for (int rr = 0; rr < 4; ++rr) {
        float v = acc[rt][rr];
        ssq[rt][rr] = fmaf(v, v, ssq[rt][rr]);
        float vm = (labrow[rt][rr] == labcol) ? -INFINITY : v;
        mxn[rt][rr] = fmaxf(mxn[rt][rr], vm);
        csA = fmaf(v, v, csA);           // col-side: sum over this lane's 16 rows
        cmA = fmaxf(cmA, vm);            // col-side: masked max (same mask, symmetric)
      }
    if (offd) {
      // reduce over q-groups (rows within the wave) -> full 64-row col partial
      csA += __shfl_xor(csA, 16, 64);
      csA += __shfl_xor(csA, 32, 64);
      cmA = fmaxf(cmA, __shfl_xor(cmA, 16, 64));
      cmA = fmaxf(cmA, __shfl_xor(cmA, 32, 64));
      if (q == 0) { colS[w][t * 16 + c] = csA; colM[w][t * 16 + c] = cmA; }
    }
  };

  auto wrap = [&](int x) { return (x < NTILES) ? x : 0; };
  int8v b0[2], b1[2], b2[2], b3[2];
  loadB(0, b0);
  loadB(1, b1);
  for (int t = 0; t < NTILES; t += 4) {
    loadB(wrap(t + 2), b2); compute(b0, t);
    loadB(wrap(t + 3), b3); compute(b1, t + 1);
    loadB(wrap(t + 4), b0); compute(b2, t + 2);
    loadB(wrap(t + 5), b1); compute(b3, t + 3);
  }

  // ---- row-side partials -> slot j
#pragma unroll
  for (int rt = 0; rt < RT; ++rt)
#pragma unroll
    for (int rr = 0; rr < 4; ++rr) {
      float s = ssq[rt][rr], m = mxn[rt][rr];
#pragma unroll
      for (int msk = 1; msk < 16; msk <<= 1) {
        s += __shfl_xor(s, msk, 64);
        m = fmaxf(m, __shfl_xor(m, msk, 64));
      }
      if (c == 0) {
        int row = rowbase + rt * 16 + q * 4 + rr;
        sumsqP[(size_t)j * N + row] = s;
        maxnegP[(size_t)j * N + row] = m;
      }
    }

  // ---- col-side partials -> slot i (combine the 4 waves' 64-row pieces)
  if (offd) {
    __syncthreads();
    float s4 = colS[0][tid] + colS[1][tid] + colS[2][tid] + colS[3][tid];
    float m4 = fmaxf(fmaxf(colM[0][tid], colM[1][tid]),
                     fmaxf(colM[2][tid], colM[3][tid]));
    const int colrow = j * CBLK + tid;
    sumsqP[(size_t)i * N + colrow] = s4;
    maxnegP[(size_t)i * N + colrow] = m4;
  }
}

// ---------------- per-row stats: norm, min_pos (bucket dots), pos_sum, flags ----------------
__global__ void k_rowstats(
    const float* __restrict__ f, const int* __restrict__ labs,
    const float* __restrict__ sumsqP, const float* __restrict__ maxnegP,
    const int* __restrict__ offs, const int* __restrict__ hist, const int* __restrict__ bucket,
    float* __restrict__ nthr2, float* __restrict__ arow,
    float* __restrict__ validf, float* __restrict__ hasnegf, float* __restrict__ posloss,
    int N)
{
  const int lane = threadIdx.x & 63;
  const int row  = blockIdx.x * 4 + (threadIdx.x >> 6);

  float s = 0.f, m = -INFINITY;
  if (lane < NSLOT) {
    s = sumsqP[(size_t)lane * N + row];
    m = maxnegP[(size_t)lane * N + row];
  }
#pragma unroll
  for (int msk = 1; msk < 64; msk <<= 1) {
    s += __shfl_xor(s, msk, 64);
    m = fmaxf(m, __shfl_xor(m, msk, 64));
  }
  float nrm = fmaxf(sqrtf(s), 1e-12f);
  float inv = 1.0f / nrm;
  float maxnegS = m * inv;
  float posth = fminf(ONE_EPS, maxnegS + MARGIN);

  const int lab = labs[row >> 1];
  const int beg = offs[lab], cnt = hist[lab];
  const float* fi = f + (size_t)row * D;
  float x0 = fi[lane], x1 = fi[lane + 64], x2 = fi[lane + 128];

  float minp = INFINITY, psum = 0.f; int pcnt = 0;
  for (int t = 0; t < cnt; ++t) {
    int smp = bucket[beg + t];
#pragma unroll
    for (int u = 0; u < 2; ++u) {
      const float* fj = f + (size_t)(smp * 2 + u) * D;
      float p = x0 * fj[lane] + x1 * fj[lane + 64] + x2 * fj[lane + 128];
#pragma unroll
      for (int msk = 1; msk < 64; msk <<= 1) p += __shfl_xor(p, msk, 64);
      minp = fminf(minp, p);
      float S = p * inv;
      if (S < posth) {
        psum += fast_exp2((THRESH - S) * (SCALE_POS * LOG2E));
        pcnt++;
      }
    }
  }

  float minS = minp * inv;
  float min_pos = (minS < ONE_EPS) ? minS : INFINITY;
  bool hneg = maxnegS > (min_pos - MARGIN);
  bool valid = hneg && (pcnt > 0);
  if (lane == 0) {
    // pass2 threshold in raw-sim units: keep/skip iff v > nthr2.
    // = max(reference neg_keep threshold, negligibility cut 0.0841*nrm).
    nthr2[row]   = fmaxf((min_pos - MARGIN) * nrm, VCUT_COEF * nrm);
    arow[row]    = inv * (SCALE_NEG * LOG2E);
    validf[row]  = valid ? 1.f : 0.f;
    hasnegf[row] = hneg ? 1.f : 0.f;
    posloss[row] = valid ? ((1.0f / SCALE_POS) * log1pf(psum)) : 0.f;
  }
}

// ---------------- pass 2: neg_sum (MX-fp8), with wave-level early exit ----------------
__global__ __launch_bounds__(256, 2) void k_pass2(
    const unsigned char* __restrict__ pk8,
    const float* __restrict__ nthr2, const float* __restrict__ arow,
    const float* __restrict__ maxnegP,
    float* __restrict__ negsumP, int N, int cps)
{
  const int lane = threadIdx.x & 63;
  const int w    = threadIdx.x >> 6;
  const int q    = lane >> 4;
  const int c    = lane & 15;
  const int cs   = blockIdx.x & (CSPLIT - 1);
  const int rbb  = blockIdx.x / CSPLIT;
  const int rowbase = rbb * RPB + w * RPW;
  const int ctile0 = (cs * cps) >> 4;
  const int ntiles = cps >> 4;

  // ---- early exit check (before any A-fragment load) ----
  // maxneg partials are 32 slots of 256 cols; this cs covers slots 2cs, 2cs+1.
  {
    int myrow = rowbase + lane;
    float mn = fmaxf(maxnegP[(size_t)(2 * cs) * N + myrow],
                     maxnegP[(size_t)(2 * cs + 1) * N + myrow]);
    float th = nthr2[myrow];
    unsigned long long bal = __ballot(mn > th);
    if (bal == 0ull) {
      negsumP[(size_t)cs * N + myrow] = 0.f;
      return;
    }
  }

  int8v afr[RT][2];
#pragma unroll
  for (int rt = 0; rt < RT; ++rt)
#pragma unroll
    for (int g = 0; g < 2; ++g) {
      afr[rt][g] = *(const int8v*)(pk8 + (size_t)((rowbase >> 4) + rt) * TILE_B8 + g * 2048 + lane * 32);
      pin_frag8(afr[rt][g]);
    }

  float nthrv[RT][4], arw[RT][4], ns[RT][4];
#pragma unroll
  for (int rt = 0; rt < RT; ++rt)
#pragma unroll
    for (int rr = 0; rr < 4; ++rr) {
      int row = rowbase + rt * 16 + q * 4 + rr;
      nthrv[rt][rr] = nthr2[row];
      arw[rt][rr]   = arow[row];
      ns[rt][rr]    = 0.f;
    }

  auto loadB = [&](int tile, int8v (&bf)[2]) {
    const unsigned char* bp = pk8 + (size_t)(ctile0 + tile) * TILE_B8 + lane * 32;
#pragma unroll
    for (int g = 0; g < 2; ++g) bf[g] = *(const int8v*)(bp + g * 2048);
  };
  auto compute = [&](const int8v (&bf)[2]) {
    f32x4 acc[RT];
#pragma unroll
    for (int rt = 0; rt < RT; ++rt) acc[rt] = 0.f;
#pragma unroll
    for (int g = 0; g < 2; ++g)
#pragma unroll
      for (int rt = 0; rt < RT; ++rt)
        acc[rt] = __builtin_amdgcn_mfma_scale_f32_16x16x128_f8f6f4(
            afr[rt][g], bf[g], acc[rt], 0, 0, 0, SCALE1, 0, SCALE1);
#pragma unroll
    for (int rt = 0; rt < RT; ++rt)
#pragma unroll
      for (int rr = 0; rr < 4; ++rr) {
        float v = acc[rt][rr];
        float e = fast_exp2(fmaf(v, arw[rt][rr], BC));
        ns[rt][rr] += (v > nthrv[rt][rr]) ? e : 0.f;
      }
  };

  int8v b0[2], b1[2];
  loadB(0, b0);
  for (int t = 0; t < ntiles; t += 2) {
    loadB(t + 1, b1);
    compute(b0);
    int nx = t + 2; nx = (nx < ntiles) ? nx : 0;
    loadB(nx, b0);
    compute(b1);
  }

#pragma unroll
  for (int rt = 0; rt < RT; ++rt)
#pragma unroll
    for (int rr = 0; rr < 4; ++rr) {
      float sv = ns[rt][rr];
#pragma unroll
      for (int msk = 1; msk < 16; msk <<= 1) sv += __shfl_xor(sv, msk, 64);
      if (c == 0) {
        int row = rowbase + rt * 16 + q * 4 + rr;
        negsumP[(size_t)cs * N + row] = sv;
      }
    }
}

// ---------------- final reduction + last-block writeback (atomic ticket) ----------------
__global__ void k_final(const float* __restrict__ negsumP, const float* __restrict__ posloss,
                        const float* __restrict__ validf, const float* __restrict__ hasnegf,
                        float* __restrict__ accum, float* __restrict__ out, int N)
{
  int i = blockIdx.x * blockDim.x + threadIdx.x;
  float lacc = 0.f, nacc = 0.f;
  if (i < N) {
    float nsum = 0.f;
    for (int cs2 = 0; cs2 < CSPLIT; ++cs2) nsum += negsumP[(size_t)cs2 * N + i];
    lacc = validf[i] * (posloss[i] + (1.0f / SCALE_NEG) * log1pf(nsum));
    nacc = 1.0f - hasnegf[i];
  }
#pragma unroll
  for (int msk = 1; msk < 64; msk <<= 1) {
    lacc += __shfl_xor(lacc, msk, 64);
    nacc += __shfl_xor(nacc, msk, 64);
  }
  __shared__ float sl[4], sn[4];
  __shared__ bool isLast;
  int wid = threadIdx.x >> 6, lane = threadIdx.x & 63;
  if (lane == 0) { sl[wid] = lacc; sn[wid] = nacc; }
  __syncthreads();
  if (threadIdx.x == 0) {
    float L = sl[0] + sl[1] + sl[2] + sl[3];
    float Nn = sn[0] + sn[1] + sn[2] + sn[3];
    atomicAdd(&accum[0], L);
    atomicAdd(&accum[1], Nn);
    __threadfence();
    int tkt = atomicAdd((int*)&accum[2], 1);
    isLast = (tkt == (int)gridDim.x - 1);
  }
  __syncthreads();
  if (isLast && threadIdx.x == 0) {
    __threadfence();
    out[0] = accum[0] / (float)N;
    out[1] = accum[1] * 100.0f / (float)N;
  }
}

extern "C" void kernel_launch(void* const* d_in, const int* in_sizes, int n_in,
                              void* d_out, int out_size, void* d_ws, size_t ws_size,
                              hipStream_t stream)
{
  (void)n_in; (void)out_size; (void)ws_size;
  const float* f    = (const float*)d_in[0];
  const int*   labs = (const int*)d_in[1];
  const int Bs = in_sizes[1];      // 4096 samples
  const int N  = 2 * Bs;           // 8192 rows

  char* ws = (char*)d_ws;
  size_t off = 0;
  auto alloc = [&](size_t bytes) -> void* {
    void* p = ws + off;
    off += (bytes + 255) & ~(size_t)255;
    return p;
  };
  unsigned char* pk8 = (unsigned char*)alloc((size_t)N * KP);
  float* sumsqP  = (float*)alloc((size_t)NSLOT * N * sizeof(float));
  float* maxnegP = (float*)alloc((size_t)NSLOT * N * sizeof(float));
  // negsumP ALIASES sumsqP: sumsqP is dead after k_rowstats; k_pass2/k_final
  // only touch maxnegP + negsumP. Keeps ws footprint near the previous
  // (known-good) version's despite the 16->32 slot partials.
  float* negsumP = sumsqP;
  float* nthr2   = (float*)alloc((size_t)N * sizeof(float));
  float* arow    = (float*)alloc((size_t)N * sizeof(float));
  float* validf  = (float*)alloc((size_t)N * sizeof(float));
  float* hasnegf = (float*)alloc((size_t)N * sizeof(float));
  float* posloss = (float*)alloc((size_t)N * sizeof(float));
  int* hist   = (int*)alloc((size_t)Bs * sizeof(int));
  int* offs   = (int*)alloc((size_t)Bs * sizeof(int));
  int* bucket = (int*)alloc((size_t)Bs * sizeof(int));
  float* accum = (float*)alloc(4 * sizeof(float));   // loss, no-neg count, ticket

  // prep: 64 pack blocks (N*8 = 65536 threads) + 1 buckets block
  k_prep<<<65, 1024, 0, stream>>>(f, pk8, N, labs, hist, offs, bucket, accum, Bs);

  // symmetric pass1: 496 off-diagonal pairs + 32 diagonals = 528 WGs (2/CU + light tail)
  k_pass1<<<NPAIR + NSLOT, 256, 0, stream>>>(pk8, labs, sumsqP, maxnegP, N);
  k_rowstats<<<N / 4, 256, 0, stream>>>(f, labs, sumsqP, maxnegP, offs, hist, bucket,
                                        nthr2, arow, validf, hasnegf, posloss, N);
  const int cps   = N / CSPLIT;           // 512 cols per split
  const int grid2 = (N / RPB) * CSPLIT;   // 32 * 16 = 512 WGs
  k_pass2<<<grid2, 256, 0, stream>>>(pk8, nthr2, arow, maxnegP, negsumP, N, cps);
  k_final<<<N / 256, 256, 0, stream>>>(negsumP, posloss, validf, hasnegf, accum, (float*)d_out, N);
}

// Round 3
// 106.048 us; speedup vs baseline: 1.2941x; 1.2941x over previous
//
#include <hip/hip_runtime.h>
#include <math.h>

typedef float  f32x4  __attribute__((ext_vector_type(4)));
typedef int    int8v  __attribute__((ext_vector_type(8)));

constexpr float MARGIN    = 0.1f;
constexpr float SCALE_POS = 2.0f;
constexpr float SCALE_NEG = 50.0f;
constexpr float THRESH    = 0.5f;
constexpr float ONE_EPS   = 1.0f - 1e-5f;
constexpr float LOG2E     = 1.4426950408889634f;
constexpr float BC        = -(SCALE_NEG * THRESH * LOG2E);   // -36.0674
// elements with a*v + BC < -30 contribute < 2^-30 ~ 9e-10 each to neg_sum;
// total skipped mass <= 8192*9e-10/50 ~ 1.6e-7 on the loss (threshold 2e-2).
constexpr float VCUT_COEF = (36.0674f - 30.0f) / (SCALE_NEG * LOG2E);  // ~0.08412 (in S units)

constexpr int D      = 192;   // feature dim
constexpr int KP     = 256;   // K padded to 2x128 for mfma_scale 16x16x128
constexpr int RT     = 4;     // row-tiles (16 rows) per wave
constexpr int RPW    = 64;    // rows per wave
constexpr int RPB    = 256;   // rows per block (4 waves)
constexpr int CSPLIT = 16;    // column splits for pass2 (512 WGs)

// symmetric pass1 tiling: 32 blocks of 256 rows/cols; upper triangle only
constexpr int NSLOT  = 32;                      // 256-col partial slots
constexpr int CBLK   = 256;                     // col-block width in pass1
constexpr int NTILES = CBLK / 16;               // 16 col-tiles per block
constexpr int NPAIR  = (NSLOT * (NSLOT - 1)) / 2;  // 496 off-diagonal pairs

// fp8 packed fragment layout (K=256 = 2 frags of 128):
// pk8[tile*4096 + g*2048 + (q*16 + c)*32 + o] = fp8(f[row=tile*16+c][k=g*128+q*32+o])
// (k >= 192 zero-padded). One wave frag load = contiguous 2KB.
constexpr int TILE_B8 = 4096;   // bytes per 16-row tile
constexpr int SCALE1  = 0x7f7f7f7f;  // e8m0 = 127 -> 2^0 = 1.0 for every block

__device__ inline float fast_exp2(float x) {
#if __has_builtin(__builtin_amdgcn_exp2f)
  return __builtin_amdgcn_exp2f(x);
#else
  return exp2f(x);
#endif
}

// pin a fragment in registers (prevent re-materialization of the global load
// inside the K-loop -- R6 showed the compiler reloads A per tile otherwise)
__device__ inline void pin_frag8(int8v& v) {
  asm volatile("" : "+v"(v));
}

// ---------------- prep: fp32->fp8 pack (blocks 0..63) + buckets (block 64) ----------------
__global__ __launch_bounds__(1024) void k_prep(
    const float* __restrict__ f, unsigned char* __restrict__ pk8, int nrows,
    const int* __restrict__ labs, int* __restrict__ hist_g, int* __restrict__ offs_g,
    int* __restrict__ bucket, float* __restrict__ accum, int n)
{
  if (blockIdx.x < 64) {
    // ---- pack: tid = r*8 + j; j indexes a 32-wide K chunk (g=j>>2, q=j&3); j>=6 -> zeros
    int gid = blockIdx.x * 1024 + threadIdx.x;
    int r = gid >> 3, j = gid & 7;
    if (r >= nrows) return;
    float x[32];
    if (j < 6) {
      const float* src = f + (size_t)r * D + j * 32;
#pragma unroll
      for (int i = 0; i < 8; ++i) {
        float4 v = *(const float4*)(src + i * 4);
        x[i * 4 + 0] = v.x; x[i * 4 + 1] = v.y; x[i * 4 + 2] = v.z; x[i * 4 + 3] = v.w;
      }
    } else {
#pragma unroll
      for (int i = 0; i < 32; ++i) x[i] = 0.f;
    }
    union { int s[8]; int8v v; } u;
#pragma unroll
    for (int i = 0; i < 8; ++i) {
      int p = __builtin_amdgcn_cvt_pk_fp8_f32(x[i * 4 + 0], x[i * 4 + 1], 0, false);
      p     = __builtin_amdgcn_cvt_pk_fp8_f32(x[i * 4 + 2], x[i * 4 + 3], p, true);
      u.s[i] = p;
    }
    int tile = r >> 4, c = r & 15, g = j >> 2, qq = j & 3;
    *(int8v*)(pk8 + (size_t)tile * TILE_B8 + g * 2048 + (qq * 16 + c) * 32) = u.v;
    return;
  }

  // ---- buckets: hist + scan + scatter + accum zero (single block)
  __shared__ int histL[4096];
  __shared__ int offsL[4096];
  __shared__ int scanb[1024];
  const int t = threadIdx.x;

  if (t < 3) accum[t] = 0.f;     // [0]=loss sum, [1]=no-neg count, [2]=ticket
  for (int i = t; i < 4096; i += 1024) histL[i] = 0;
  __syncthreads();
  for (int i = t; i < n; i += 1024) atomicAdd(&histL[labs[i]], 1);
  __syncthreads();
  int base = t * 4;
  int v[4]; int ls = 0;
  for (int k = 0; k < 4; ++k) { v[k] = ls; ls += histL[base + k]; }
  scanb[t] = ls;
  __syncthreads();
  for (int o = 1; o < 1024; o <<= 1) {
    int x = (t >= o) ? scanb[t - o] : 0;
    __syncthreads();
    scanb[t] += x;
    __syncthreads();
  }
  int ebase = scanb[t] - ls;
  for (int k = 0; k < 4; ++k) {
    offsL[base + k] = ebase + v[k];
    offs_g[base + k] = ebase + v[k];
    hist_g[base + k] = histL[base + k];
  }
  __syncthreads();
  for (int i = t; i < 4096; i += 1024) histL[i] = 0;
  __syncthreads();
  for (int i = t; i < n; i += 1024) {
    int lab = labs[i];
    int p = atomicAdd(&histL[lab], 1);
    bucket[offsL[lab] + p] = i;
  }
}

// ---------------- pass 1 (SYMMETRIC): sumsq + max over negatives ----------------
// Upper-triangle 256x256 block pairs (i<=j). Off-diagonal WGs emit BOTH the
// row-side partials (slot j, rows of block i) and, via sim(r,c)=sim(c,r), the
// col-side partials (slot i, rows of block j). Every (slot,row) pair has
// exactly one writer -> no atomics. Diagonals (i==j) emit row-side only.
//
// R2 post-mortem: quad-buffered B + col-side epilogue spilled to scratch
// (WRITE_SIZE 23 MB vs 2 MB logical; all pipes <11%). Double-buffer B here
// (-32 VGPR) to get back under the allocator's cliff.
__global__ __launch_bounds__(256, 2) void k_pass1(
    const unsigned char* __restrict__ pk8, const int* __restrict__ labs,
    float* __restrict__ sumsqP, float* __restrict__ maxnegP, int N)
{
  __shared__ int   ldsLab[CBLK];
  __shared__ float colS[4][CBLK];
  __shared__ float colM[4][CBLK];

  const int tid  = threadIdx.x;
  const int lane = tid & 63;
  const int w    = tid >> 6;
  const int q    = lane >> 4;
  const int c    = lane & 15;

  // pair decode: bids [0,NPAIR) = off-diagonal (i<j); [NPAIR, NPAIR+32) = diagonal
  int i, j;
  if ((int)blockIdx.x < NPAIR) {
    int t = blockIdx.x; i = 0;
    while (t >= NSLOT - 1 - i) { t -= NSLOT - 1 - i; ++i; }
    j = i + 1 + t;
  } else {
    i = j = blockIdx.x - NPAIR;
  }
  const bool offd = (i != j);
  const int rowbase = i * CBLK + w * RPW;
  const int ctile0  = j * NTILES;

  ldsLab[tid] = labs[(j * CBLK + tid) >> 1];

  // A fragments: load once, pin resident (RT x 2 x 8 VGPR = 64)
  int8v afr[RT][2];
#pragma unroll
  for (int rt = 0; rt < RT; ++rt)
#pragma unroll
    for (int g = 0; g < 2; ++g) {
      afr[rt][g] = *(const int8v*)(pk8 + (size_t)((rowbase >> 4) + rt) * TILE_B8 + g * 2048 + lane * 32);
      pin_frag8(afr[rt][g]);
    }

  int labrow[RT][4];
#pragma unroll
  for (int rt = 0; rt < RT; ++rt)
#pragma unroll
    for (int rr = 0; rr < 4; ++rr)
      labrow[rt][rr] = labs[(rowbase + rt * 16 + q * 4 + rr) >> 1];

  float ssq[RT][4], mxn[RT][4];
#pragma unroll
  for (int rt = 0; rt < RT; ++rt)
#pragma unroll
    for (int rr = 0; rr < 4; ++rr) { ssq[rt][rr] = 0.f; mxn[rt][rr] = -INFINITY; }

  __syncthreads();   // ldsLab ready

  auto loadB = [&](int tile, int8v (&bf)[2]) {
    const unsigned char* bp = pk8 + (size_t)(ctile0 + tile) * TILE_B8 + lane * 32;
#pragma unroll
    for (int g = 0; g < 2; ++g) bf[g] = *(const int8v*)(bp + g * 2048);
  };
  auto compute = [&](const int8v (&bf)[2], int t) {
    const int labcol = ldsLab[t * 16 + c];
    f32x4 acc[RT];
#pragma unroll
    for (int rt = 0; rt < RT; ++rt) acc[rt] = 0.f;
#pragma unroll
    for (int g = 0; g < 2; ++g)
#pragma unroll
      for (int rt = 0; rt < RT; ++rt)
        acc[rt] = __builtin_amdgcn_mfma_scale_f32_16x16x128_f8f6f4(
            afr[rt][g], bf[g], acc[rt], 0, 0, 0, SCALE1, 0, SCALE1);
    float csA = 0.f, cmA = -INFINITY;
#pragma unroll
    for (int rt = 0; rt < RT; ++rt)
#pragma unroll
      for (int rr = 0; rr < 4; ++rr) {
        float v = acc[rt][rr];
        ssq[rt][rr] = fmaf(v, v, ssq[rt][rr]);
        float vm = (labrow[rt][rr] == labcol) ? -INFINITY : v;
        mxn[rt][rr] = fmaxf(mxn[rt][rr], vm);
        csA = fmaf(v, v, csA);           // col-side: sum over this lane's 16 rows
        cmA = fmaxf(cmA, vm);            // col-side: masked max (same mask, symmetric)
      }
    if (offd) {
      // reduce over q-groups (rows within the wave) -> full 64-row col partial
      csA += __shfl_xor(csA, 16, 64);
      csA += __shfl_xor(csA, 32, 64);
      cmA = fmaxf(cmA, __shfl_xor(cmA, 16, 64));
      cmA = fmaxf(cmA, __shfl_xor(cmA, 32, 64));
      if (q == 0) { colS[w][t * 16 + c] = csA; colM[w][t * 16 + c] = cmA; }
    }
  };

  // double-buffered B rotation (2-deep prefetch, same as pass2)
  int8v b0[2], b1[2];
  loadB(0, b0);
  for (int t = 0; t < NTILES; t += 2) {
    loadB(t + 1, b1);
    compute(b0, t);
    int nx = t + 2; nx = (nx < NTILES) ? nx : 0;
    loadB(nx, b0);
    compute(b1, t + 1);
  }

  // ---- row-side partials -> slot j
#pragma unroll
  for (int rt = 0; rt < RT; ++rt)
#pragma unroll
    for (int rr = 0; rr < 4; ++rr) {
      float s = ssq[rt][rr], m = mxn[rt][rr];
#pragma unroll
      for (int msk = 1; msk < 16; msk <<= 1) {
        s += __shfl_xor(s, msk, 64);
        m = fmaxf(m, __shfl_xor(m, msk, 64));
      }
      if (c == 0) {
        int row = rowbase + rt * 16 + q * 4 + rr;
        sumsqP[(size_t)j * N + row] = s;
        maxnegP[(size_t)j * N + row] = m;
      }
    }

  // ---- col-side partials -> slot i (combine the 4 waves' 64-row pieces)
  if (offd) {
    __syncthreads();
    float s4 = colS[0][tid] + colS[1][tid] + colS[2][tid] + colS[3][tid];
    float m4 = fmaxf(fmaxf(colM[0][tid], colM[1][tid]),
                     fmaxf(colM[2][tid], colM[3][tid]));
    const int colrow = j * CBLK + tid;
    sumsqP[(size_t)i * N + colrow] = s4;
    maxnegP[(size_t)i * N + colrow] = m4;
  }
}

// ---------------- per-row stats: norm, min_pos (bucket dots), pos_sum, flags ----------------
__global__ void k_rowstats(
    const float* __restrict__ f, const int* __restrict__ labs,
    const float* __restrict__ sumsqP, const float* __restrict__ maxnegP,
    const int* __restrict__ offs, const int* __restrict__ hist, const int* __restrict__ bucket,
    float* __restrict__ nthr2, float* __restrict__ arow,
    float* __restrict__ validf, float* __restrict__ hasnegf, float* __restrict__ posloss,
    int N)
{
  const int lane = threadIdx.x & 63;
  const int row  = blockIdx.x * 4 + (threadIdx.x >> 6);

  float s = 0.f, m = -INFINITY;
  if (lane < NSLOT) {
    s = sumsqP[(size_t)lane * N + row];
    m = maxnegP[(size_t)lane * N + row];
  }
#pragma unroll
  for (int msk = 1; msk < 64; msk <<= 1) {
    s += __shfl_xor(s, msk, 64);
    m = fmaxf(m, __shfl_xor(m, msk, 64));
  }
  float nrm = fmaxf(sqrtf(s), 1e-12f);
  float inv = 1.0f / nrm;
  float maxnegS = m * inv;
  float posth = fminf(ONE_EPS, maxnegS + MARGIN);

  const int lab = labs[row >> 1];
  const int beg = offs[lab], cnt = hist[lab];
  const float* fi = f + (size_t)row * D;
  float x0 = fi[lane], x1 = fi[lane + 64], x2 = fi[lane + 128];

  float minp = INFINITY, psum = 0.f; int pcnt = 0;
  for (int t = 0; t < cnt; ++t) {
    int smp = bucket[beg + t];
#pragma unroll
    for (int u = 0; u < 2; ++u) {
      const float* fj = f + (size_t)(smp * 2 + u) * D;
      float p = x0 * fj[lane] + x1 * fj[lane + 64] + x2 * fj[lane + 128];
#pragma unroll
      for (int msk = 1; msk < 64; msk <<= 1) p += __shfl_xor(p, msk, 64);
      minp = fminf(minp, p);
      float S = p * inv;
      if (S < posth) {
        psum += fast_exp2((THRESH - S) * (SCALE_POS * LOG2E));
        pcnt++;
      }
    }
  }

  float minS = minp * inv;
  float min_pos = (minS < ONE_EPS) ? minS : INFINITY;
  bool hneg = maxnegS > (min_pos - MARGIN);
  bool valid = hneg && (pcnt > 0);
  if (lane == 0) {
    // pass2 threshold in raw-sim units: keep/skip iff v > nthr2.
    // = max(reference neg_keep threshold, negligibility cut 0.0841*nrm).
    nthr2[row]   = fmaxf((min_pos - MARGIN) * nrm, VCUT_COEF * nrm);
    arow[row]    = inv * (SCALE_NEG * LOG2E);
    validf[row]  = valid ? 1.f : 0.f;
    hasnegf[row] = hneg ? 1.f : 0.f;
    posloss[row] = valid ? ((1.0f / SCALE_POS) * log1pf(psum)) : 0.f;
  }
}

// ---------------- pass 2: neg_sum (MX-fp8), with wave-level early exit ----------------
__global__ __launch_bounds__(256, 2) void k_pass2(
    const unsigned char* __restrict__ pk8,
    const float* __restrict__ nthr2, const float* __restrict__ arow,
    const float* __restrict__ maxnegP,
    float* __restrict__ negsumP, int N, int cps)
{
  const int lane = threadIdx.x & 63;
  const int w    = threadIdx.x >> 6;
  const int q    = lane >> 4;
  const int c    = lane & 15;
  const int cs   = blockIdx.x & (CSPLIT - 1);
  const int rbb  = blockIdx.x / CSPLIT;
  const int rowbase = rbb * RPB + w * RPW;
  const int ctile0 = (cs * cps) >> 4;
  const int ntiles = cps >> 4;

  // ---- early exit check (before any A-fragment load) ----
  // maxneg partials are 32 slots of 256 cols; this cs covers slots 2cs, 2cs+1.
  {
    int myrow = rowbase + lane;
    float mn = fmaxf(maxnegP[(size_t)(2 * cs) * N + myrow],
                     maxnegP[(size_t)(2 * cs + 1) * N + myrow]);
    float th = nthr2[myrow];
    unsigned long long bal = __ballot(mn > th);
    if (bal == 0ull) {
      negsumP[(size_t)cs * N + myrow] = 0.f;
      return;
    }
  }

  int8v afr[RT][2];
#pragma unroll
  for (int rt = 0; rt < RT; ++rt)
#pragma unroll
    for (int g = 0; g < 2; ++g) {
      afr[rt][g] = *(const int8v*)(pk8 + (size_t)((rowbase >> 4) + rt) * TILE_B8 + g * 2048 + lane * 32);
      pin_frag8(afr[rt][g]);
    }

  float nthrv[RT][4], arw[RT][4], ns[RT][4];
#pragma unroll
  for (int rt = 0; rt < RT; ++rt)
#pragma unroll
    for (int rr = 0; rr < 4; ++rr) {
      int row = rowbase + rt * 16 + q * 4 + rr;
      nthrv[rt][rr] = nthr2[row];
      arw[rt][rr]   = arow[row];
      ns[rt][rr]    = 0.f;
    }

  auto loadB = [&](int tile, int8v (&bf)[2]) {
    const unsigned char* bp = pk8 + (size_t)(ctile0 + tile) * TILE_B8 + lane * 32;
#pragma unroll
    for (int g = 0; g < 2; ++g) bf[g] = *(const int8v*)(bp + g * 2048);
  };
  auto compute = [&](const int8v (&bf)[2]) {
    f32x4 acc[RT];
#pragma unroll
    for (int rt = 0; rt < RT; ++rt) acc[rt] = 0.f;
#pragma unroll
    for (int g = 0; g < 2; ++g)
#pragma unroll
      for (int rt = 0; rt < RT; ++rt)
        acc[rt] = __builtin_amdgcn_mfma_scale_f32_16x16x128_f8f6f4(
            afr[rt][g], bf[g], acc[rt], 0, 0, 0, SCALE1, 0, SCALE1);
#pragma unroll
    for (int rt = 0; rt < RT; ++rt)
#pragma unroll
      for (int rr = 0; rr < 4; ++rr) {
        float v = acc[rt][rr];
        float e = fast_exp2(fmaf(v, arw[rt][rr], BC));
        ns[rt][rr] += (v > nthrv[rt][rr]) ? e : 0.f;
      }
  };

  int8v b0[2], b1[2];
  loadB(0, b0);
  for (int t = 0; t < ntiles; t += 2) {
    loadB(t + 1, b1);
    compute(b0);
    int nx = t + 2; nx = (nx < ntiles) ? nx : 0;
    loadB(nx, b0);
    compute(b1);
  }

#pragma unroll
  for (int rt = 0; rt < RT; ++rt)
#pragma unroll
    for (int rr = 0; rr < 4; ++rr) {
      float sv = ns[rt][rr];
#pragma unroll
      for (int msk = 1; msk < 16; msk <<= 1) sv += __shfl_xor(sv, msk, 64);
      if (c == 0) {
        int row = rowbase + rt * 16 + q * 4 + rr;
        negsumP[(size_t)cs * N + row] = sv;
      }
    }
}

// ---------------- final reduction + last-block writeback (atomic ticket) ----------------
__global__ void k_final(const float* __restrict__ negsumP, const float* __restrict__ posloss,
                        const float* __restrict__ validf, const float* __restrict__ hasnegf,
                        float* __restrict__ accum, float* __restrict__ out, int N)
{
  int i = blockIdx.x * blockDim.x + threadIdx.x;
  float lacc = 0.f, nacc = 0.f;
  if (i < N) {
    float nsum = 0.f;
    for (int cs2 = 0; cs2 < CSPLIT; ++cs2) nsum += negsumP[(size_t)cs2 * N + i];
    lacc = validf[i] * (posloss[i] + (1.0f / SCALE_NEG) * log1pf(nsum));
    nacc = 1.0f - hasnegf[i];
  }
#pragma unroll
  for (int msk = 1; msk < 64; msk <<= 1) {
    lacc += __shfl_xor(lacc, msk, 64);
    nacc += __shfl_xor(nacc, msk, 64);
  }
  __shared__ float sl[4], sn[4];
  __shared__ bool isLast;
  int wid = threadIdx.x >> 6, lane = threadIdx.x & 63;
  if (lane == 0) { sl[wid] = lacc; sn[wid] = nacc; }
  __syncthreads();
  if (threadIdx.x == 0) {
    float L = sl[0] + sl[1] + sl[2] + sl[3];
    float Nn = sn[0] + sn[1] + sn[2] + sn[3];
    atomicAdd(&accum[0], L);
    atomicAdd(&accum[1], Nn);
    __threadfence();
    int tkt = atomicAdd((int*)&accum[2], 1);
    isLast = (tkt == (int)gridDim.x - 1);
  }
  __syncthreads();
  if (isLast && threadIdx.x == 0) {
    __threadfence();
    out[0] = accum[0] / (float)N;
    out[1] = accum[1] * 100.0f / (float)N;
  }
}

extern "C" void kernel_launch(void* const* d_in, const int* in_sizes, int n_in,
                              void* d_out, int out_size, void* d_ws, size_t ws_size,
                              hipStream_t stream)
{
  (void)n_in; (void)out_size; (void)ws_size;
  const float* f    = (const float*)d_in[0];
  const int*   labs = (const int*)d_in[1];
  const int Bs = in_sizes[1];      // 4096 samples
  const int N  = 2 * Bs;           // 8192 rows

  char* ws = (char*)d_ws;
  size_t off = 0;
  auto alloc = [&](size_t bytes) -> void* {
    void* p = ws + off;
    off += (bytes + 255) & ~(size_t)255;
    return p;
  };
  unsigned char* pk8 = (unsigned char*)alloc((size_t)N * KP);
  float* sumsqP  = (float*)alloc((size_t)NSLOT * N * sizeof(float));
  float* maxnegP = (float*)alloc((size_t)NSLOT * N * sizeof(float));
  // negsumP ALIASES sumsqP: sumsqP is dead after k_rowstats; k_pass2/k_final
  // only touch maxnegP + negsumP.
  float* negsumP = sumsqP;
  float* nthr2   = (float*)alloc((size_t)N * sizeof(float));
  float* arow    = (float*)alloc((size_t)N * sizeof(float));
  float* validf  = (float*)alloc((size_t)N * sizeof(float));
  float* hasnegf = (float*)alloc((size_t)N * sizeof(float));
  float* posloss = (float*)alloc((size_t)N * sizeof(float));
  int* hist   = (int*)alloc((size_t)Bs * sizeof(int));
  int* offs   = (int*)alloc((size_t)Bs * sizeof(int));
  int* bucket = (int*)alloc((size_t)Bs * sizeof(int));
  float* accum = (float*)alloc(4 * sizeof(float));   // loss, no-neg count, ticket

  // prep: 64 pack blocks (N*8 = 65536 threads) + 1 buckets block
  k_prep<<<65, 1024, 0, stream>>>(f, pk8, N, labs, hist, offs, bucket, accum, Bs);

  // symmetric pass1: 496 off-diagonal pairs + 32 diagonals = 528 WGs
  k_pass1<<<NPAIR + NSLOT, 256, 0, stream>>>(pk8, labs, sumsqP, maxnegP, N);
  k_rowstats<<<N / 4, 256, 0, stream>>>(f, labs, sumsqP, maxnegP, offs, hist, bucket,
                                        nthr2, arow, validf, hasnegf, posloss, N);
  const int cps   = N / CSPLIT;           // 512 cols per split
  const int grid2 = (N / RPB) * CSPLIT;   // 32 * 16 = 512 WGs
  k_pass2<<<grid2, 256, 0, stream>>>(pk8, nthr2, arow, maxnegP, negsumP, N, cps);
  k_final<<<N / 256, 256, 0, stream>>>(negsumP, posloss, validf, hasnegf, accum, (float*)d_out, N);
}